// Round 7
// baseline (154.648 us; speedup 1.0000x reference)
//
#include <hip/hip_runtime.h>

// ============================================================================
// ROUND 7 = ATTRIBUTION ROUND: fused kernel launched TWICE (idempotent).
// dur_R7 - dur_R6 = fused-kernel duration + ~1.5us launch gap.
// Kernels themselves are UNCHANGED from round 6 for clean algebra.
// ============================================================================

#define CCH 256
#define HH  256
#define WW  256
#define HWSZ (HH * WW)
#define NROI 512
#define RBIN 7
#define NBIN (RBIN * RBIN)                    // 49
#define TFEAT_BYTES ((size_t)HWSZ * CCH * 2)  // 32 MiB bf16 HWC

typedef float vfloat4 __attribute__((ext_vector_type(4)));

__device__ __forceinline__ unsigned short f2bf_rne(float f) {
    unsigned u = __float_as_uint(f);
    u = (u + 0x7fffu + ((u >> 16) & 1u)) >> 16;
    return (unsigned short)u;
}

// ---------------- Kernel 1: (C,H,W) fp32 -> (H,W,C) bf16 transpose ----------
__global__ __launch_bounds__(256)
void transpose_chw_to_hwc_bf16(const float* __restrict__ feat,
                               unsigned short* __restrict__ tfeat)
{
    __shared__ float tile[64][65];            // [c_local][hw_local], 16.6 KB
    const int t   = threadIdx.x;              // 0..255
    const int hw0 = blockIdx.x * 64;
    const int c0  = blockIdx.y * 64;

    #pragma unroll
    for (int j = 0; j < 4; ++j) {
        const int cl = (t >> 4) + j * 16;     // 0..63 over passes
        const int hl = (t & 15) * 4;          // 0,4,..,60
        const vfloat4 v = __builtin_nontemporal_load(
            (const vfloat4*)(feat + (size_t)(c0 + cl) * HWSZ + hw0 + hl));
        tile[cl][hl]     = v.x;
        tile[cl][hl + 1] = v.y;
        tile[cl][hl + 2] = v.z;
        tile[cl][hl + 3] = v.w;
    }
    __syncthreads();
    #pragma unroll
    for (int j = 0; j < 4; ++j) {
        const int hl = (t >> 4) + j * 16;     // 0..63 over passes
        const int cl = (t & 15) * 4;          // 0,4,..,60
        ushort4 w;
        w.x = f2bf_rne(tile[cl][hl]);
        w.y = f2bf_rne(tile[cl + 1][hl]);
        w.z = f2bf_rne(tile[cl + 2][hl]);
        w.w = f2bf_rne(tile[cl + 3][hl]);
        *(ushort4*)(tfeat + (size_t)(hw0 + hl) * CCH + c0 + cl) = w;
    }
}

// ---------------- Kernel 2: fused sample + pool + broadcast (UNCHANGED) -----
__global__ __launch_bounds__(1024)
void roialign_fused(const unsigned short* __restrict__ tfeat,
                    const float* __restrict__ rois,
                    float* __restrict__ out)
{
    const int n    = blockIdx.x;
    const int t    = threadIdx.x;
    const int wave = t >> 6;                  // 0..15
    const int lane = t & 63;
    const int half = lane >> 5;               // point selector within pair
    const int cOff = (lane & 31) * 8;         // 8 channels per lane

    __shared__ float pooled[NBIN];

    const float y0 = rois[n * 4 + 0];
    const float x0 = rois[n * 4 + 1];
    const float sh = (rois[n * 4 + 2] - y0) / (float)RBIN;
    const float sw = (rois[n * 4 + 3] - x0) / (float)RBIN;

    for (int bin = wave; bin < NBIN; bin += 16) {
        const int by = bin / RBIN;
        const int bx = bin % RBIN;

        float acc[8];
        #pragma unroll
        for (int k = 0; k < 8; ++k) acc[k] = -INFINITY;

        #pragma unroll
        for (int i = 0; i < 2; ++i) {
            const int point = i * 2 + half;   // 0..3 over (i, half)
            const int sy = point >> 1;
            const int sx = point & 1;

            const float y = y0 + sh * (float)by +
                            ((sy == 0) ? (sh / 3.0f) : (2.0f * sh / 3.0f));
            const float x = x0 + sw * (float)bx +
                            ((sx == 0) ? (sw / 3.0f) : (2.0f * sw / 3.0f));

            int iy1 = (int)floorf(y);
            int iy2 = iy1 + 1;
            int ix1 = (int)floorf(x);
            int ix2 = ix1 + 1;
            iy1 = min(max(iy1, 0), HH - 1);
            iy2 = min(max(iy2, 0), HH - 1);
            ix1 = min(max(ix1, 0), WW - 1);
            ix2 = min(max(ix2, 0), WW - 1);

            const float wy1 = y - (float)iy1;
            const float wy2 = (float)iy2 - y;
            const float wx1 = x - (float)ix1;
            const float wx2 = (float)ix2 - x;

            const uint4 A = *(const uint4*)(tfeat + (size_t)(iy1 * WW + ix1) * CCH + cOff);
            const uint4 B = *(const uint4*)(tfeat + (size_t)(iy1 * WW + ix2) * CCH + cOff);
            const uint4 C = *(const uint4*)(tfeat + (size_t)(iy2 * WW + ix1) * CCH + cOff);
            const uint4 D = *(const uint4*)(tfeat + (size_t)(iy2 * WW + ix2) * CCH + cOff);
            const unsigned* ap = (const unsigned*)&A;
            const unsigned* bp = (const unsigned*)&B;
            const unsigned* cp = (const unsigned*)&C;
            const unsigned* dp = (const unsigned*)&D;

            #pragma unroll
            for (int k = 0; k < 4; ++k) {
                const unsigned ua = ap[k], ub = bp[k], uc = cp[k], ud = dp[k];
                {
                    const float f11 = __uint_as_float(ua << 16);
                    const float f12 = __uint_as_float(ub << 16);
                    const float f21 = __uint_as_float(uc << 16);
                    const float f22 = __uint_as_float(ud << 16);
                    const float p = f11 * wx2 + f12 * wx1;
                    const float q = f21 * wx2 + f22 * wx1;
                    acc[2 * k] = fmaxf(acc[2 * k], p * wy2 + q * wy1);
                }
                {
                    const float f11 = __uint_as_float(ua & 0xffff0000u);
                    const float f12 = __uint_as_float(ub & 0xffff0000u);
                    const float f21 = __uint_as_float(uc & 0xffff0000u);
                    const float f22 = __uint_as_float(ud & 0xffff0000u);
                    const float p = f11 * wx2 + f12 * wx1;
                    const float q = f21 * wx2 + f22 * wx1;
                    acc[2 * k + 1] = fmaxf(acc[2 * k + 1], p * wy2 + q * wy1);
                }
            }
        }

        float m = fmaxf(fmaxf(fmaxf(acc[0], acc[1]), fmaxf(acc[2], acc[3])),
                        fmaxf(fmaxf(acc[4], acc[5]), fmaxf(acc[6], acc[7])));

        #pragma unroll
        for (int off = 32; off > 0; off >>= 1)
            m = fmaxf(m, __shfl_xor(m, off, 64));

        if (lane == 0) pooled[bin] = m;
    }
    __syncthreads();

    float* o = out + (size_t)n * (CCH * NBIN);
    #pragma unroll
    for (int k = 0; k < 13; ++k) {            // 13*1024 >= 12544
        const int idx = t + k * 1024;
        if (idx < CCH * NBIN)
            __builtin_nontemporal_store(pooled[idx % NBIN], o + idx);
    }
}

// ---------------- Fallback (round-1 direct kernel, used if ws too small) ----
__global__ __launch_bounds__(256)
void roialign_direct_kernel(const float* __restrict__ feat,
                            const float* __restrict__ rois,
                            float* __restrict__ out)
{
    const int n = blockIdx.x;
    const int t = threadIdx.x;
    __shared__ float ptmax[196];
    __shared__ float pooled[NBIN];

    const float y0  = rois[n * 4 + 0];
    const float x0  = rois[n * 4 + 1];
    const float sh  = (rois[n * 4 + 2] - y0) / (float)RBIN;
    const float sw  = (rois[n * 4 + 3] - x0) / (float)RBIN;

    const bool active = (t < 196);
    int off11 = 0, off12 = 0, off21 = 0, off22 = 0;
    float wx1 = 0.f, wx2 = 0.f, wy1 = 0.f, wy2 = 0.f;
    if (active) {
        const int py = t / 14, px = t % 14;
        const int by = py >> 1, sy = py & 1;
        const int bx = px >> 1, sx = px & 1;
        const float y = y0 + sh * (float)by + ((sy == 0) ? (sh / 3.0f) : (2.0f * sh / 3.0f));
        const float x = x0 + sw * (float)bx + ((sx == 0) ? (sw / 3.0f) : (2.0f * sw / 3.0f));
        int iy1 = (int)floorf(y), iy2 = iy1 + 1;
        int ix1 = (int)floorf(x), ix2 = ix1 + 1;
        iy1 = min(max(iy1, 0), HH - 1); iy2 = min(max(iy2, 0), HH - 1);
        ix1 = min(max(ix1, 0), WW - 1); ix2 = min(max(ix2, 0), WW - 1);
        wy1 = y - (float)iy1; wy2 = (float)iy2 - y;
        wx1 = x - (float)ix1; wx2 = (float)ix2 - x;
        off11 = iy1 * WW + ix1; off12 = iy1 * WW + ix2;
        off21 = iy2 * WW + ix1; off22 = iy2 * WW + ix2;
    }
    if (active) {
        float m = -INFINITY;
        const float* f = feat;
        #pragma unroll 4
        for (int c = 0; c < CCH; ++c) {
            const float p = f[off11] * wx2 + f[off12] * wx1;
            const float q = f[off21] * wx2 + f[off22] * wx1;
            m = fmaxf(m, p * wy2 + q * wy1);
            f += HWSZ;
        }
        ptmax[t] = m;
    }
    __syncthreads();
    if (t < NBIN) {
        const int by = t / RBIN, bx = t % RBIN;
        const int p00 = (2 * by) * 14 + 2 * bx;
        pooled[t] = fmaxf(fmaxf(ptmax[p00], ptmax[p00 + 1]),
                          fmaxf(ptmax[p00 + 14], ptmax[p00 + 15]));
    }
    __syncthreads();
    float* o = out + (size_t)n * (CCH * NBIN);
    for (int idx = t; idx < CCH * NBIN; idx += 256)
        o[idx] = pooled[idx % NBIN];
}

extern "C" void kernel_launch(void* const* d_in, const int* in_sizes, int n_in,
                              void* d_out, int out_size, void* d_ws, size_t ws_size,
                              hipStream_t stream)
{
    const float* feat = (const float*)d_in[0];   // (256,256,256) fp32
    const float* rois = (const float*)d_in[1];   // (512,4) fp32
    float* out = (float*)d_out;                  // (512,256,7,7) fp32

    if (ws_size < TFEAT_BYTES) {
        roialign_direct_kernel<<<NROI, 256, 0, stream>>>(feat, rois, out);
        return;
    }

    unsigned short* tfeat = (unsigned short*)d_ws;

    dim3 tgrid(HWSZ / 64, CCH / 64);
    transpose_chw_to_hwc_bf16<<<tgrid, 256, 0, stream>>>(feat, tfeat);

    // ATTRIBUTION: launch fused twice (idempotent). dur delta vs R6 = F.
    roialign_fused<<<NROI, 1024, 0, stream>>>(tfeat, rois, out);
    roialign_fused<<<NROI, 1024, 0, stream>>>(tfeat, rois, out);
}

// Round 8
// 130.177 us; speedup vs baseline: 1.1880x; 1.1880x over previous
//
#include <hip/hip_runtime.h>

#define CCH 256
#define HH  256
#define WW  256
#define HWSZ (HH * WW)
#define NROI 512
#define RBIN 7
#define NBIN (RBIN * RBIN)                    // 49
#define TFEAT_BYTES ((size_t)HWSZ * CCH * 2)  // 32 MiB bf16 HWC

typedef float vfloat4 __attribute__((ext_vector_type(4)));

__device__ __forceinline__ unsigned short f2bf_rne(float f) {
    unsigned u = __float_as_uint(f);
    u = (u + 0x7fffu + ((u >> 16) & 1u)) >> 16;
    return (unsigned short)u;
}

// ---------------- Kernel 1: (C,H,W) fp32 -> (H,W,C) bf16 transpose ----------
// R8 rework (fused kernel untouched -- single-variable experiment):
//  * tile row stride 68 floats = 272 B, 16B-aligned every row -> the read
//    pass stores vfloat4 as one ds_write_b128 (was 4x ds_write_b32 at
//    stride 65).
//  * all 4 nontemporal global loads issued into registers BEFORE any LDS
//    write -> 64 B outstanding per thread instead of ~16 B.
// Bank pattern: b128 writes sweep all 32 banks; write-pass column reads are
// 2 lanes/bank -- free on CDNA4 (m136).
__global__ __launch_bounds__(256)
void transpose_chw_to_hwc_bf16(const float* __restrict__ feat,
                               unsigned short* __restrict__ tfeat)
{
    __shared__ float tile[64][68];            // 17.4 KB, rows 16B-aligned
    const int t   = threadIdx.x;              // 0..255
    const int hw0 = blockIdx.x * 64;
    const int c0  = blockIdx.y * 64;

    const int cl_r = (t >> 4);                // 0..15 (+j*16)
    const int hl_r = (t & 15) * 4;            // 0,4,..,60

    vfloat4 v[4];
    #pragma unroll
    for (int j = 0; j < 4; ++j) {
        v[j] = __builtin_nontemporal_load(
            (const vfloat4*)(feat + (size_t)(c0 + cl_r + j * 16) * HWSZ + hw0 + hl_r));
    }
    #pragma unroll
    for (int j = 0; j < 4; ++j) {
        *(vfloat4*)&tile[cl_r + j * 16][hl_r] = v[j];   // ds_write_b128
    }
    __syncthreads();

    const int cl_w = (t & 15) * 4;            // 0,4,..,60
    #pragma unroll
    for (int j = 0; j < 4; ++j) {
        const int hl = (t >> 4) + j * 16;     // 0..63 over passes
        ushort4 w;
        w.x = f2bf_rne(tile[cl_w][hl]);
        w.y = f2bf_rne(tile[cl_w + 1][hl]);
        w.z = f2bf_rne(tile[cl_w + 2][hl]);
        w.w = f2bf_rne(tile[cl_w + 3][hl]);
        // 16 lanes (same hl) cover 64 consecutive channels -> 128 B segment
        *(ushort4*)(tfeat + (size_t)(hw0 + hl) * CCH + c0 + cl_w) = w;
    }
}

// ---------------- Kernel 2: fused sample + pool + broadcast (UNCHANGED R6) --
__global__ __launch_bounds__(1024)
void roialign_fused(const unsigned short* __restrict__ tfeat,
                    const float* __restrict__ rois,
                    float* __restrict__ out)
{
    const int n    = blockIdx.x;
    const int t    = threadIdx.x;
    const int wave = t >> 6;                  // 0..15
    const int lane = t & 63;
    const int half = lane >> 5;               // point selector within pair
    const int cOff = (lane & 31) * 8;         // 8 channels per lane

    __shared__ float pooled[NBIN];

    const float y0 = rois[n * 4 + 0];
    const float x0 = rois[n * 4 + 1];
    const float sh = (rois[n * 4 + 2] - y0) / (float)RBIN;
    const float sw = (rois[n * 4 + 3] - x0) / (float)RBIN;

    for (int bin = wave; bin < NBIN; bin += 16) {
        const int by = bin / RBIN;
        const int bx = bin % RBIN;

        float acc[8];
        #pragma unroll
        for (int k = 0; k < 8; ++k) acc[k] = -INFINITY;

        #pragma unroll
        for (int i = 0; i < 2; ++i) {
            const int point = i * 2 + half;   // 0..3 over (i, half)
            const int sy = point >> 1;
            const int sx = point & 1;

            const float y = y0 + sh * (float)by +
                            ((sy == 0) ? (sh / 3.0f) : (2.0f * sh / 3.0f));
            const float x = x0 + sw * (float)bx +
                            ((sx == 0) ? (sw / 3.0f) : (2.0f * sw / 3.0f));

            int iy1 = (int)floorf(y);
            int iy2 = iy1 + 1;
            int ix1 = (int)floorf(x);
            int ix2 = ix1 + 1;
            iy1 = min(max(iy1, 0), HH - 1);
            iy2 = min(max(iy2, 0), HH - 1);
            ix1 = min(max(ix1, 0), WW - 1);
            ix2 = min(max(ix2, 0), WW - 1);

            const float wy1 = y - (float)iy1;
            const float wy2 = (float)iy2 - y;
            const float wx1 = x - (float)ix1;
            const float wx2 = (float)ix2 - x;

            const uint4 A = *(const uint4*)(tfeat + (size_t)(iy1 * WW + ix1) * CCH + cOff);
            const uint4 B = *(const uint4*)(tfeat + (size_t)(iy1 * WW + ix2) * CCH + cOff);
            const uint4 C = *(const uint4*)(tfeat + (size_t)(iy2 * WW + ix1) * CCH + cOff);
            const uint4 D = *(const uint4*)(tfeat + (size_t)(iy2 * WW + ix2) * CCH + cOff);
            const unsigned* ap = (const unsigned*)&A;
            const unsigned* bp = (const unsigned*)&B;
            const unsigned* cp = (const unsigned*)&C;
            const unsigned* dp = (const unsigned*)&D;

            #pragma unroll
            for (int k = 0; k < 4; ++k) {
                const unsigned ua = ap[k], ub = bp[k], uc = cp[k], ud = dp[k];
                {
                    const float f11 = __uint_as_float(ua << 16);
                    const float f12 = __uint_as_float(ub << 16);
                    const float f21 = __uint_as_float(uc << 16);
                    const float f22 = __uint_as_float(ud << 16);
                    const float p = f11 * wx2 + f12 * wx1;
                    const float q = f21 * wx2 + f22 * wx1;
                    acc[2 * k] = fmaxf(acc[2 * k], p * wy2 + q * wy1);
                }
                {
                    const float f11 = __uint_as_float(ua & 0xffff0000u);
                    const float f12 = __uint_as_float(ub & 0xffff0000u);
                    const float f21 = __uint_as_float(uc & 0xffff0000u);
                    const float f22 = __uint_as_float(ud & 0xffff0000u);
                    const float p = f11 * wx2 + f12 * wx1;
                    const float q = f21 * wx2 + f22 * wx1;
                    acc[2 * k + 1] = fmaxf(acc[2 * k + 1], p * wy2 + q * wy1);
                }
            }
        }

        float m = fmaxf(fmaxf(fmaxf(acc[0], acc[1]), fmaxf(acc[2], acc[3])),
                        fmaxf(fmaxf(acc[4], acc[5]), fmaxf(acc[6], acc[7])));

        #pragma unroll
        for (int off = 32; off > 0; off >>= 1)
            m = fmaxf(m, __shfl_xor(m, off, 64));

        if (lane == 0) pooled[bin] = m;
    }
    __syncthreads();

    float* o = out + (size_t)n * (CCH * NBIN);
    #pragma unroll
    for (int k = 0; k < 13; ++k) {            // 13*1024 >= 12544
        const int idx = t + k * 1024;
        if (idx < CCH * NBIN)
            __builtin_nontemporal_store(pooled[idx % NBIN], o + idx);
    }
}

// ---------------- Fallback (round-1 direct kernel, used if ws too small) ----
__global__ __launch_bounds__(256)
void roialign_direct_kernel(const float* __restrict__ feat,
                            const float* __restrict__ rois,
                            float* __restrict__ out)
{
    const int n = blockIdx.x;
    const int t = threadIdx.x;
    __shared__ float ptmax[196];
    __shared__ float pooled[NBIN];

    const float y0  = rois[n * 4 + 0];
    const float x0  = rois[n * 4 + 1];
    const float sh  = (rois[n * 4 + 2] - y0) / (float)RBIN;
    const float sw  = (rois[n * 4 + 3] - x0) / (float)RBIN;

    const bool active = (t < 196);
    int off11 = 0, off12 = 0, off21 = 0, off22 = 0;
    float wx1 = 0.f, wx2 = 0.f, wy1 = 0.f, wy2 = 0.f;
    if (active) {
        const int py = t / 14, px = t % 14;
        const int by = py >> 1, sy = py & 1;
        const int bx = px >> 1, sx = px & 1;
        const float y = y0 + sh * (float)by + ((sy == 0) ? (sh / 3.0f) : (2.0f * sh / 3.0f));
        const float x = x0 + sw * (float)bx + ((sx == 0) ? (sw / 3.0f) : (2.0f * sw / 3.0f));
        int iy1 = (int)floorf(y), iy2 = iy1 + 1;
        int ix1 = (int)floorf(x), ix2 = ix1 + 1;
        iy1 = min(max(iy1, 0), HH - 1); iy2 = min(max(iy2, 0), HH - 1);
        ix1 = min(max(ix1, 0), WW - 1); ix2 = min(max(ix2, 0), WW - 1);
        wy1 = y - (float)iy1; wy2 = (float)iy2 - y;
        wx1 = x - (float)ix1; wx2 = (float)ix2 - x;
        off11 = iy1 * WW + ix1; off12 = iy1 * WW + ix2;
        off21 = iy2 * WW + ix1; off22 = iy2 * WW + ix2;
    }
    if (active) {
        float m = -INFINITY;
        const float* f = feat;
        #pragma unroll 4
        for (int c = 0; c < CCH; ++c) {
            const float p = f[off11] * wx2 + f[off12] * wx1;
            const float q = f[off21] * wx2 + f[off22] * wx1;
            m = fmaxf(m, p * wy2 + q * wy1);
            f += HWSZ;
        }
        ptmax[t] = m;
    }
    __syncthreads();
    if (t < NBIN) {
        const int by = t / RBIN, bx = t % RBIN;
        const int p00 = (2 * by) * 14 + 2 * bx;
        pooled[t] = fmaxf(fmaxf(ptmax[p00], ptmax[p00 + 1]),
                          fmaxf(ptmax[p00 + 14], ptmax[p00 + 15]));
    }
    __syncthreads();
    float* o = out + (size_t)n * (CCH * NBIN);
    for (int idx = t; idx < CCH * NBIN; idx += 256)
        o[idx] = pooled[idx % NBIN];
}

extern "C" void kernel_launch(void* const* d_in, const int* in_sizes, int n_in,
                              void* d_out, int out_size, void* d_ws, size_t ws_size,
                              hipStream_t stream)
{
    const float* feat = (const float*)d_in[0];   // (256,256,256) fp32
    const float* rois = (const float*)d_in[1];   // (512,4) fp32
    float* out = (float*)d_out;                  // (512,256,7,7) fp32

    if (ws_size < TFEAT_BYTES) {
        roialign_direct_kernel<<<NROI, 256, 0, stream>>>(feat, rois, out);
        return;
    }

    unsigned short* tfeat = (unsigned short*)d_ws;

    dim3 tgrid(HWSZ / 64, CCH / 64);
    transpose_chw_to_hwc_bf16<<<tgrid, 256, 0, stream>>>(feat, tfeat);

    roialign_fused<<<NROI, 1024, 0, stream>>>(tfeat, rois, out);
}